// Round 6
// baseline (516.817 us; speedup 1.0000x reference)
//
#include <hip/hip_runtime.h>
#include <hip/hip_bf16.h>

// Problem constants: B=32, S=512, D=256, H=8, DH=32
#define SCALE_QK 0.17677669529663687f  // 1/sqrt(32)

typedef __attribute__((ext_vector_type(8))) short short8;  // 8 bf16 (4 VGPRs)
typedef __attribute__((ext_vector_type(4))) float f32x4;

__device__ __forceinline__ ushort f2bf(float f) {  // fp32 -> bf16 RNE
  unsigned u = __float_as_uint(f);
  return (ushort)((u + 0x7FFF + ((u >> 16) & 1)) >> 16);
}

// C[m,n] = sum_k A[m,k]*W[n,k] + bias[n];  M=16384, N=256, K=256
// mode 0: C fp32 row-major [m][n]
// mode 1: C bf16 in q/k layout [b,h,s,e] (b=m>>9,s=m&511,h=n>>5,e=n&31),
//         value scaled by `scale` before rounding.
__global__ __launch_bounds__(256) void gemm_proj(const float *__restrict__ A,
                                                 const float *__restrict__ W,
                                                 const float *__restrict__ bias,
                                                 void *__restrict__ Cout,
                                                 int mode, float scale) {
  __shared__ float As[16][68];
  __shared__ float Ws[16][68];
  const int tid = threadIdx.x;
  const int m0 = blockIdx.x * 64;
  const int n0 = blockIdx.y * 64;
  const int ty = tid >> 4, tx = tid & 15;
  const int lm = tid >> 2, lk4 = (tid & 3) * 4;
  const float *Ald = A + (m0 + lm) * 256 + lk4;
  const float *Wld = W + (n0 + lm) * 256 + lk4;
  float acc[4][4] = {};
  for (int k0 = 0; k0 < 256; k0 += 16) {
    const float4 av = *(const float4 *)(Ald + k0);
    const float4 wv = *(const float4 *)(Wld + k0);
    __syncthreads();
    As[lk4 + 0][lm] = av.x; As[lk4 + 1][lm] = av.y;
    As[lk4 + 2][lm] = av.z; As[lk4 + 3][lm] = av.w;
    Ws[lk4 + 0][lm] = wv.x; Ws[lk4 + 1][lm] = wv.y;
    Ws[lk4 + 2][lm] = wv.z; Ws[lk4 + 3][lm] = wv.w;
    __syncthreads();
#pragma unroll
    for (int kk = 0; kk < 16; ++kk) {
      const float4 a = *(const float4 *)&As[kk][ty * 4];
      const float4 w = *(const float4 *)&Ws[kk][tx * 4];
      const float ar[4] = {a.x, a.y, a.z, a.w};
      const float wr[4] = {w.x, w.y, w.z, w.w};
#pragma unroll
      for (int r = 0; r < 4; ++r)
#pragma unroll
        for (int c = 0; c < 4; ++c) acc[r][c] += ar[r] * wr[c];
    }
  }
  const float4 bs = *(const float4 *)(bias + n0 + tx * 4);
  const float br[4] = {bs.x, bs.y, bs.z, bs.w};
#pragma unroll
  for (int r = 0; r < 4; ++r) {
    const int m = m0 + ty * 4 + r;
    float o[4];
#pragma unroll
    for (int c = 0; c < 4; ++c) o[c] = acc[r][c] + br[c];
    if (mode == 0) {
      *(float4 *)((float *)Cout + m * 256 + n0 + tx * 4) =
          make_float4(o[0], o[1], o[2], o[3]);
    } else {
      const int b = m >> 9, s = m & 511;
      const int n = n0 + tx * 4, h = n >> 5, e = n & 31;
      ushort4 o4;
      o4.x = f2bf(o[0] * scale); o4.y = f2bf(o[1] * scale);
      o4.z = f2bf(o[2] * scale); o4.w = f2bf(o[3] * scale);
      *(ushort4 *)((ushort *)Cout + (((b << 3) + h) * 512 + s) * 32 + e) = o4;
    }
  }
}

// Fused scores (MFMA bf16) + diag-mask + sparsemax + head-average.
// Q (pre-scaled by 1/sqrt(32)) and K are bf16 [B,H,S,32].
// Block = 4 waves on the same 16 q-rows; wave w owns col tiles 8w..8w+7.
// MFMA 16x16x32: A/B frags are direct 16B row loads; C/D: col = jg*16+l15,
// row = quad*4+reg.  Per-lane live state 64 floats -> no spills.
//
// Sparsemax: tau* >= M-1 (max - tau* <= sum(z-tau*) = 1). Starting Michelot
// at tau0 = M-1 keeps every iterate inside S0 = {z > M-1}: tau1 =
// M - (sum(M-z)+1)/k > M-1 because each M-z < 1; sets shrink monotonically
// after that, so the COMPACT list of S0 (~13/512 entries for this data)
// suffices for an exact solve. Pipeline per head:
//   (1) one scan appends candidates > M-1 to per-row LDS lists (ds atomics),
//   (2) Michelot runs WAVE-LOCALLY (all waves redundantly solve all 16 rows:
//       row = lane&15, 4 lanes/row hold <=32 reg-cached entries; LDS overflow
//       path beyond 32 keeps exactness) with 4 shfls/iter and NO barriers,
//   (3) tau broadcast via in-wave shfl, avgacc epilogue.
// 3 barriers/head total (vs ~20 in the block-synchronized version).
__global__ __launch_bounds__(256) void attn_sparsemax_mfma(
    const ushort *__restrict__ Q, const ushort *__restrict__ K,
    float *__restrict__ avg) {
  __shared__ float list[16][516];  // stride 516: quad-partners 2-way max
  __shared__ int cnt[16];
  __shared__ float redmax[4][16];  // [wave][row]
  const int tid = threadIdx.x;
  const int w = tid >> 6, lane = tid & 63;
  const int quad = lane >> 4, l15 = lane & 15;
  const int s0 = blockIdx.x * 16;
  const int j0 = blockIdx.x;  // global col tile holding this row block's diag
  const int b = blockIdx.y;
  const int jw0 = w * 8;  // first global col tile of this wave

  float avgacc[8][4] = {};
#pragma unroll 1
  for (int h = 0; h < 8; ++h) {
    const ushort *qh = Q + (((b << 3) + h) * 512 + s0) * 32;
    const ushort *kh = K + ((b << 3) + h) * 512 * 32;
    const short8 aq = *(const short8 *)(qh + l15 * 32 + quad * 8);
    f32x4 acc[8];
#pragma unroll
    for (int jl = 0; jl < 8; ++jl) {
      const short8 bk =
          *(const short8 *)(kh + ((jw0 + jl) * 16 + l15) * 32 + quad * 8);
      acc[jl] = __builtin_amdgcn_mfma_f32_16x16x32_bf16(
          aq, bk, (f32x4){0.f, 0.f, 0.f, 0.f}, 0, 0, 0);
    }
    // diagonal mask: col jg*16+l15 == row s0+quad*4+r
    if ((j0 >> 3) == w) {
      const int jl = j0 & 7;
#pragma unroll
      for (int r = 0; r < 4; ++r)
        if (l15 == quad * 4 + r) acc[jl][r] = -1e30f;
    }
    // wave-partial row max over this wave's 128 cols
    float mm[4];
#pragma unroll
    for (int r = 0; r < 4; ++r) {
      float m = acc[0][r];
#pragma unroll
      for (int jl = 1; jl < 8; ++jl) m = fmaxf(m, acc[jl][r]);
      m = fmaxf(m, __shfl_xor(m, 1, 64));
      m = fmaxf(m, __shfl_xor(m, 2, 64));
      m = fmaxf(m, __shfl_xor(m, 4, 64));
      m = fmaxf(m, __shfl_xor(m, 8, 64));
      mm[r] = m;
    }
    __syncthreads();  // [A] prior head's list/redmax reads complete
    if (tid < 16) cnt[tid] = 0;
    if (l15 == 0) {
#pragma unroll
      for (int r = 0; r < 4; ++r) redmax[w][quad * 4 + r] = mm[r];
    }
    __syncthreads();  // [B]
    // threshold tau0 = M-1 per C-layout row
    float thr[4];
#pragma unroll
    for (int r = 0; r < 4; ++r) {
      const int row = quad * 4 + r;
      thr[r] = fmaxf(fmaxf(redmax[0][row], redmax[1][row]),
                     fmaxf(redmax[2][row], redmax[3][row])) -
               1.0f;
    }
    // compaction: append candidates (z > M-1) to per-row lists
#pragma unroll
    for (int jl = 0; jl < 8; ++jl) {
#pragma unroll
      for (int r = 0; r < 4; ++r) {
        const float zv = acc[jl][r];
        if (zv > thr[r]) {
          const int row = quad * 4 + r;
          const int idx = atomicAdd(&cnt[row], 1);
          list[row][idx] = zv;
        }
      }
    }
    __syncthreads();  // [C] lists complete
    // wave-local Michelot on compact lists (row = l15, 4 lanes/row)
    const int myrow = l15;
    const int n = cnt[myrow];
    float vreg[8];
#pragma unroll
    for (int s = 0; s < 8; ++s) {
      const int idx = quad + 4 * s;
      vreg[s] = (idx < n) ? list[myrow][idx] : -3e38f;
    }
    float tau = fmaxf(fmaxf(redmax[0][myrow], redmax[1][myrow]),
                      fmaxf(redmax[2][myrow], redmax[3][myrow])) -
                1.0f;
    float cOld = -1.f;
#pragma unroll 1
    for (int it = 0; it < 40; ++it) {
      float s = 0.f, c = 0.f;
#pragma unroll
      for (int q = 0; q < 8; ++q) {
        if (vreg[q] > tau) { s += vreg[q]; c += 1.f; }
      }
      for (int i = 32 + quad; i < n; i += 4) {  // overflow path (rare)
        const float v = list[myrow][i];
        if (v > tau) { s += v; c += 1.f; }
      }
      s += __shfl_xor(s, 16, 64);
      s += __shfl_xor(s, 32, 64);
      c += __shfl_xor(c, 16, 64);
      c += __shfl_xor(c, 32, 64);
      const bool stable = (c == cOld);
      if (__all(stable)) break;  // all 16 rows' supports fixed -> taus exact
      if (!stable) { tau = (s - 1.f) / c; cOld = c; }
    }
    // broadcast tau to C-layout lanes and accumulate head-average
#pragma unroll
    for (int r = 0; r < 4; ++r) {
      const float taur = __shfl(tau, quad * 4 + r, 64);
#pragma unroll
      for (int jl = 0; jl < 8; ++jl)
        avgacc[jl][r] += fmaxf(acc[jl][r] - taur, 0.f);
    }
  }
  // write avg (includes 1/H)
#pragma unroll
  for (int r = 0; r < 4; ++r) {
    const int s = s0 + quad * 4 + r;
    float *dst = avg + ((b * 512 + s) << 9) + jw0 * 16 + l15;
#pragma unroll
    for (int jl = 0; jl < 8; ++jl) dst[jl * 16] = avgacc[jl][r] * 0.125f;
  }
}

// Batched NN GEMM: C[b] = A[b] (512x512) * V[b] (512x256)
__global__ __launch_bounds__(256) void gemm_av(const float *__restrict__ A,
                                               const float *__restrict__ V,
                                               float *__restrict__ C) {
  __shared__ float As[16][68];
  __shared__ float Bs[16][68];
  const int tid = threadIdx.x;
  const int b = blockIdx.z;
  const int m0 = blockIdx.x * 64, n0 = blockIdx.y * 64;
  const float *Ab = A + b * 512 * 512;
  const float *Vb = V + b * 512 * 256;
  float *Cb = C + b * 512 * 256;
  const int ty = tid >> 4, tx = tid & 15;
  const int lm = tid >> 2, lk4 = (tid & 3) * 4;
  const int lkb = tid >> 4, lnb = (tid & 15) * 4;
  float acc[4][4] = {};
  for (int k0 = 0; k0 < 512; k0 += 16) {
    const float4 av = *(const float4 *)(Ab + (m0 + lm) * 512 + k0 + lk4);
    const float4 bv = *(const float4 *)(Vb + (k0 + lkb) * 256 + n0 + lnb);
    __syncthreads();
    As[lk4 + 0][lm] = av.x; As[lk4 + 1][lm] = av.y;
    As[lk4 + 2][lm] = av.z; As[lk4 + 3][lm] = av.w;
    *(float4 *)&Bs[lkb][lnb] = bv;
    __syncthreads();
#pragma unroll
    for (int kk = 0; kk < 16; ++kk) {
      const float4 a = *(const float4 *)&As[kk][ty * 4];
      const float4 w = *(const float4 *)&Bs[kk][tx * 4];
      const float ar[4] = {a.x, a.y, a.z, a.w};
      const float wr[4] = {w.x, w.y, w.z, w.w};
#pragma unroll
      for (int r = 0; r < 4; ++r)
#pragma unroll
        for (int c = 0; c < 4; ++c) acc[r][c] += ar[r] * wr[c];
    }
  }
#pragma unroll
  for (int r = 0; r < 4; ++r) {
    float4 o;
    o.x = acc[r][0]; o.y = acc[r][1]; o.z = acc[r][2]; o.w = acc[r][3];
    *(float4 *)(Cb + (m0 + ty * 4 + r) * 256 + n0 + tx * 4) = o;
  }
}

extern "C" void kernel_launch(void* const* d_in, const int* in_sizes, int n_in,
                              void* d_out, int out_size, void* d_ws, size_t ws_size,
                              hipStream_t stream) {
  const float *x  = (const float *)d_in[0];
  const float *Wq = (const float *)d_in[1];
  const float *bq = (const float *)d_in[2];
  const float *Wk = (const float *)d_in[3];
  const float *bk = (const float *)d_in[4];
  const float *Wv = (const float *)d_in[5];
  const float *bv = (const float *)d_in[6];
  const float *Wo = (const float *)d_in[7];
  const float *bo = (const float *)d_in[8];

  float *out = (float *)d_out;                 // [B,S,D]
  float *avg = out + 32 * 512 * 256;           // [B,S,S]

  // workspace (peak 32 MB): qbf 8MB | kbf 8MB | v 16MB ; mid reuses qbf+kbf
  ushort *qbf = (ushort *)d_ws;                // [B,H,S,32] bf16 (pre-scaled)
  ushort *kbf = qbf + 32 * 8 * 512 * 32;       // [B,H,S,32] bf16
  float  *v   = (float *)(kbf + 32 * 8 * 512 * 32);  // [B,S,256] fp32
  float  *mid = (float *)d_ws;                 // [B,S,256] fp32 (after attn)

  const dim3 blk(256);
  const dim3 gProj(256, 4);

  gemm_proj<<<gProj, blk, 0, stream>>>(x, Wq, bq, qbf, 1, SCALE_QK);
  gemm_proj<<<gProj, blk, 0, stream>>>(x, Wk, bk, kbf, 1, 1.0f);
  attn_sparsemax_mfma<<<dim3(32, 32), blk, 0, stream>>>(qbf, kbf, avg);
  gemm_proj<<<gProj, blk, 0, stream>>>(x, Wv, bv, v, 0, 1.0f);
  gemm_av<<<dim3(8, 4, 32), blk, 0, stream>>>(avg, v, mid);
  gemm_proj<<<gProj, blk, 0, stream>>>(mid, Wo, bo, out, 0, 1.0f);
}

// Round 7
// 351.642 us; speedup vs baseline: 1.4697x; 1.4697x over previous
//
#include <hip/hip_runtime.h>
#include <hip/hip_bf16.h>

// Problem constants: B=32, S=512, D=256, H=8, DH=32
#define SCALE_QK 0.17677669529663687f  // 1/sqrt(32)

typedef __attribute__((ext_vector_type(8))) short short8;  // 8 bf16 (4 VGPRs)
typedef __attribute__((ext_vector_type(4))) float f32x4;

__device__ __forceinline__ ushort f2bf(float f) {  // fp32 -> bf16 RNE
  unsigned u = __float_as_uint(f);
  return (ushort)((u + 0x7FFF + ((u >> 16) & 1)) >> 16);
}

// C[m,n] = sum_k A[m,k]*W[n,k] + bias[n];  M=16384, N=256, K=256
// mode 0: C fp32 row-major [m][n]
// mode 1: C bf16 in q/k layout [b,h,s,e] (b=m>>9,s=m&511,h=n>>5,e=n&31),
//         value scaled by `scale` before rounding.
__global__ __launch_bounds__(256) void gemm_proj(const float *__restrict__ A,
                                                 const float *__restrict__ W,
                                                 const float *__restrict__ bias,
                                                 void *__restrict__ Cout,
                                                 int mode, float scale) {
  __shared__ float As[16][68];
  __shared__ float Ws[16][68];
  const int tid = threadIdx.x;
  const int m0 = blockIdx.x * 64;
  const int n0 = blockIdx.y * 64;
  const int ty = tid >> 4, tx = tid & 15;
  const int lm = tid >> 2, lk4 = (tid & 3) * 4;
  const float *Ald = A + (m0 + lm) * 256 + lk4;
  const float *Wld = W + (n0 + lm) * 256 + lk4;
  float acc[4][4] = {};
  for (int k0 = 0; k0 < 256; k0 += 16) {
    const float4 av = *(const float4 *)(Ald + k0);
    const float4 wv = *(const float4 *)(Wld + k0);
    __syncthreads();
    As[lk4 + 0][lm] = av.x; As[lk4 + 1][lm] = av.y;
    As[lk4 + 2][lm] = av.z; As[lk4 + 3][lm] = av.w;
    Ws[lk4 + 0][lm] = wv.x; Ws[lk4 + 1][lm] = wv.y;
    Ws[lk4 + 2][lm] = wv.z; Ws[lk4 + 3][lm] = wv.w;
    __syncthreads();
#pragma unroll
    for (int kk = 0; kk < 16; ++kk) {
      const float4 a = *(const float4 *)&As[kk][ty * 4];
      const float4 w = *(const float4 *)&Ws[kk][tx * 4];
      const float ar[4] = {a.x, a.y, a.z, a.w};
      const float wr[4] = {w.x, w.y, w.z, w.w};
#pragma unroll
      for (int r = 0; r < 4; ++r)
#pragma unroll
        for (int c = 0; c < 4; ++c) acc[r][c] += ar[r] * wr[c];
    }
  }
  const float4 bs = *(const float4 *)(bias + n0 + tx * 4);
  const float br[4] = {bs.x, bs.y, bs.z, bs.w};
#pragma unroll
  for (int r = 0; r < 4; ++r) {
    const int m = m0 + ty * 4 + r;
    float o[4];
#pragma unroll
    for (int c = 0; c < 4; ++c) o[c] = acc[r][c] + br[c];
    if (mode == 0) {
      *(float4 *)((float *)Cout + m * 256 + n0 + tx * 4) =
          make_float4(o[0], o[1], o[2], o[3]);
    } else {
      const int b = m >> 9, s = m & 511;
      const int n = n0 + tx * 4, h = n >> 5, e = n & 31;
      ushort4 o4;
      o4.x = f2bf(o[0] * scale); o4.y = f2bf(o[1] * scale);
      o4.z = f2bf(o[2] * scale); o4.w = f2bf(o[3] * scale);
      *(ushort4 *)((ushort *)Cout + (((b << 3) + h) * 512 + s) * 32 + e) = o4;
    }
  }
}

// Fused scores (MFMA bf16, TRANSPOSED operands) + diag-mask + sparsemax +
// head-average.  Q (pre-scaled by 1/sqrt(32)) and K are bf16 [B,H,S,32].
//
// Block = 4 waves on the same 16 q-rows.  Score phase: mfma(A=K-tile, B=Q)
// gives D[m=col-in-tile][n=qrow]: lane (quad,l15) holds row s0+l15, cols
// w*128+jl*16+quad*4+{0..3} -> 4 CONSECUTIVE cols of ONE row per reg quad.
// One XOR-swizzled LDS round trip per head (8 ds_write_b128 + 8 ds_read_b128,
// conflict-free; 2 barriers) redistributes to the solve layout: lane
// (quad,l15) owns row 4w+quad completely, cols 64c+4*l15+r in z[8][4].
// The row's 32-per-lane values live in the 16 lanes sharing quad ->
// row max / Michelot sum+count reduce with shfl_xor(1,2,4,8): the entire
// sparsemax is wave-local, LDS-free, barrier-free, atomic-free, and each
// row is solved exactly once (no 4x redundancy as in R5/R6).
// Michelot from tau0 = rowmax-1 (provably >= all iterates' support),
// support-size fixed point -> exact tau.
__global__ __launch_bounds__(256) void attn_sparsemax_mfma(
    const ushort *__restrict__ Q, const ushort *__restrict__ K,
    float *__restrict__ avg) {
  __shared__ f32x4 sc[16 * 128];  // 32 KB score tile, chunk-XOR swizzle
  const int tid = threadIdx.x;
  const int w = tid >> 6, lane = tid & 63;
  const int quad = lane >> 4, l15 = lane & 15;
  const int s0 = blockIdx.x * 16;
  const int b = blockIdx.y;
  const int myrow = 4 * w + quad;  // row this lane owns in the solve phase
  const int sglob = s0 + myrow;

  float avgacc[8][4] = {};
#pragma unroll 1
  for (int h = 0; h < 8; ++h) {
    const ushort *qh = Q + (((b << 3) + h) * 512 + s0) * 32;
    const ushort *kh = K + ((b << 3) + h) * 512 * 32;
    const short8 bq = *(const short8 *)(qh + l15 * 32 + quad * 8);
    f32x4 acc[8];
#pragma unroll
    for (int jl = 0; jl < 8; ++jl) {
      const short8 ak =
          *(const short8 *)(kh + (w * 128 + jl * 16 + l15) * 32 + quad * 8);
      acc[jl] = __builtin_amdgcn_mfma_f32_16x16x32_bf16(
          ak, bq, (f32x4){0.f, 0.f, 0.f, 0.f}, 0, 0, 0);
      // lane holds score[s0+l15][w*128 + jl*16 + quad*4 + r]
    }
    __syncthreads();  // prior head's solve-phase reads complete
#pragma unroll
    for (int jl = 0; jl < 8; ++jl) {
      const int ch = 32 * w + 4 * jl + quad;          // logical 16B chunk
      sc[l15 * 128 + (ch ^ (l15 & 7))] = acc[jl];     // XOR swizzle
    }
    __syncthreads();
    f32x4 z[8];
#pragma unroll
    for (int c = 0; c < 8; ++c) {
      const int ch = l15 + 16 * c;
      z[c] = sc[myrow * 128 + (ch ^ (myrow & 7))];
      // z[c][r] = score[sglob][64*c + 4*l15 + r]
    }
    // diagonal mask: col == sglob
#pragma unroll
    for (int c = 0; c < 8; ++c)
#pragma unroll
      for (int r = 0; r < 4; ++r)
        if (64 * c + 4 * l15 + r == sglob) z[c][r] = -1e30f;
    // row max across this row's 16 lanes
    float M = z[0][0];
#pragma unroll
    for (int c = 0; c < 8; ++c)
#pragma unroll
      for (int r = 0; r < 4; ++r) M = fmaxf(M, z[c][r]);
    M = fmaxf(M, __shfl_xor(M, 1, 64));
    M = fmaxf(M, __shfl_xor(M, 2, 64));
    M = fmaxf(M, __shfl_xor(M, 4, 64));
    M = fmaxf(M, __shfl_xor(M, 8, 64));
    float tau = M - 1.0f;
    int cOld = -1;
#pragma unroll 1
    for (int it = 0; it < 32; ++it) {
      float s = 0.f;
      int c = 0;
#pragma unroll
      for (int cc = 0; cc < 8; ++cc)
#pragma unroll
        for (int r = 0; r < 4; ++r) {
          const bool p = z[cc][r] > tau;
          s += p ? z[cc][r] : 0.f;
          c += p ? 1 : 0;
        }
      s += __shfl_xor(s, 1, 64);
      s += __shfl_xor(s, 2, 64);
      s += __shfl_xor(s, 4, 64);
      s += __shfl_xor(s, 8, 64);
      c += __shfl_xor(c, 1, 64);
      c += __shfl_xor(c, 2, 64);
      c += __shfl_xor(c, 4, 64);
      c += __shfl_xor(c, 8, 64);
      const bool stable = (c == cOld);
      if (__all(stable)) break;  // all 4 rows of this wave fixed -> exact
      if (!stable) {
        tau = (s - 1.f) / (float)c;
        cOld = c;
      }
    }
    // accumulate head-average (whole row in-lane, tau in-lane)
#pragma unroll
    for (int c = 0; c < 8; ++c)
#pragma unroll
      for (int r = 0; r < 4; ++r)
        avgacc[c][r] += fmaxf(z[c][r] - tau, 0.f);
  }
  // epilogue: perfectly-structured row writes (includes 1/H)
  float *dst = avg + ((b * 512 + sglob) << 9) + 4 * l15;
#pragma unroll
  for (int c = 0; c < 8; ++c) {
    float4 o;
    o.x = avgacc[c][0] * 0.125f;
    o.y = avgacc[c][1] * 0.125f;
    o.z = avgacc[c][2] * 0.125f;
    o.w = avgacc[c][3] * 0.125f;
    *(float4 *)(dst + 64 * c) = o;
  }
}

// Batched NN GEMM: C[b] = A[b] (512x512) * V[b] (512x256)
__global__ __launch_bounds__(256) void gemm_av(const float *__restrict__ A,
                                               const float *__restrict__ V,
                                               float *__restrict__ C) {
  __shared__ float As[16][68];
  __shared__ float Bs[16][68];
  const int tid = threadIdx.x;
  const int b = blockIdx.z;
  const int m0 = blockIdx.x * 64, n0 = blockIdx.y * 64;
  const float *Ab = A + b * 512 * 512;
  const float *Vb = V + b * 512 * 256;
  float *Cb = C + b * 512 * 256;
  const int ty = tid >> 4, tx = tid & 15;
  const int lm = tid >> 2, lk4 = (tid & 3) * 4;
  const int lkb = tid >> 4, lnb = (tid & 15) * 4;
  float acc[4][4] = {};
  for (int k0 = 0; k0 < 512; k0 += 16) {
    const float4 av = *(const float4 *)(Ab + (m0 + lm) * 512 + k0 + lk4);
    const float4 bv = *(const float4 *)(Vb + (k0 + lkb) * 256 + n0 + lnb);
    __syncthreads();
    As[lk4 + 0][lm] = av.x; As[lk4 + 1][lm] = av.y;
    As[lk4 + 2][lm] = av.z; As[lk4 + 3][lm] = av.w;
    *(float4 *)&Bs[lkb][lnb] = bv;
    __syncthreads();
#pragma unroll
    for (int kk = 0; kk < 16; ++kk) {
      const float4 a = *(const float4 *)&As[kk][ty * 4];
      const float4 w = *(const float4 *)&Bs[kk][tx * 4];
      const float ar[4] = {a.x, a.y, a.z, a.w};
      const float wr[4] = {w.x, w.y, w.z, w.w};
#pragma unroll
      for (int r = 0; r < 4; ++r)
#pragma unroll
        for (int c = 0; c < 4; ++c) acc[r][c] += ar[r] * wr[c];
    }
  }
#pragma unroll
  for (int r = 0; r < 4; ++r) {
    float4 o;
    o.x = acc[r][0]; o.y = acc[r][1]; o.z = acc[r][2]; o.w = acc[r][3];
    *(float4 *)(Cb + (m0 + ty * 4 + r) * 256 + n0 + tx * 4) = o;
  }
}

extern "C" void kernel_launch(void* const* d_in, const int* in_sizes, int n_in,
                              void* d_out, int out_size, void* d_ws, size_t ws_size,
                              hipStream_t stream) {
  const float *x  = (const float *)d_in[0];
  const float *Wq = (const float *)d_in[1];
  const float *bq = (const float *)d_in[2];
  const float *Wk = (const float *)d_in[3];
  const float *bk = (const float *)d_in[4];
  const float *Wv = (const float *)d_in[5];
  const float *bv = (const float *)d_in[6];
  const float *Wo = (const float *)d_in[7];
  const float *bo = (const float *)d_in[8];

  float *out = (float *)d_out;                 // [B,S,D]
  float *avg = out + 32 * 512 * 256;           // [B,S,S]

  // workspace (peak 32 MB): qbf 8MB | kbf 8MB | v 16MB ; mid reuses qbf+kbf
  ushort *qbf = (ushort *)d_ws;                // [B,H,S,32] bf16 (pre-scaled)
  ushort *kbf = qbf + 32 * 8 * 512 * 32;       // [B,H,S,32] bf16
  float  *v   = (float *)(kbf + 32 * 8 * 512 * 32);  // [B,S,256] fp32
  float  *mid = (float *)d_ws;                 // [B,S,256] fp32 (after attn)

  const dim3 blk(256);
  const dim3 gProj(256, 4);

  gemm_proj<<<gProj, blk, 0, stream>>>(x, Wq, bq, qbf, 1, SCALE_QK);
  gemm_proj<<<gProj, blk, 0, stream>>>(x, Wk, bk, kbf, 1, 1.0f);
  attn_sparsemax_mfma<<<dim3(32, 32), blk, 0, stream>>>(qbf, kbf, avg);
  gemm_proj<<<gProj, blk, 0, stream>>>(x, Wv, bv, v, 0, 1.0f);
  gemm_av<<<dim3(8, 4, 32), blk, 0, stream>>>(avg, v, mid);
  gemm_proj<<<gProj, blk, 0, stream>>>(mid, Wo, bo, out, 0, 1.0f);
}

// Round 8
// 308.707 us; speedup vs baseline: 1.6741x; 1.1391x over previous
//
#include <hip/hip_runtime.h>
#include <hip/hip_bf16.h>

// Problem constants: B=32, S=512, D=256, H=8, DH=32
#define SCALE_QK 0.17677669529663687f  // 1/sqrt(32)

typedef __attribute__((ext_vector_type(8))) short short8;  // 8 bf16 (4 VGPRs)
typedef __attribute__((ext_vector_type(4))) float f32x4;

__device__ __forceinline__ ushort f2bf(float f) {  // fp32 -> bf16 RNE
  unsigned u = __float_as_uint(f);
  return (ushort)((u + 0x7FFF + ((u >> 16) & 1)) >> 16);
}

// Convert x (16384x256 fp32) and the four 256x256 weight mats to bf16.
__global__ __launch_bounds__(256) void cvt_bf16(
    const float *__restrict__ x, const float *__restrict__ w0,
    const float *__restrict__ w1, const float *__restrict__ w2,
    const float *__restrict__ w3, ushort *__restrict__ xbf,
    ushort *__restrict__ wbf) {
  const long i = (long)blockIdx.x * 256 + threadIdx.x;  // one float4 each
  const long NX4 = 16384L * 256 / 4;                    // 1048576
  const float *src;
  ushort4 *dst;
  long k;
  if (i < NX4) {
    src = x; k = i; dst = (ushort4 *)xbf;
  } else {
    const long j = i - NX4;  // [0, 65536)
    const int which = (int)(j >> 14);
    k = j & 16383;
    src = which == 0 ? w0 : which == 1 ? w1 : which == 2 ? w2 : w3;
    dst = (ushort4 *)(wbf + which * 65536L);
  }
  const float4 v = ((const float4 *)src)[k];
  ushort4 o;
  o.x = f2bf(v.x); o.y = f2bf(v.y); o.z = f2bf(v.z); o.w = f2bf(v.w);
  dst[k] = o;
}

// Unified NT bf16 MFMA GEMM: C[i][j] = dot(Y-row i, X-row j) (+bias).
// mfma(A=X-tile rows, B=Y-tile rows) -> D[n=l15 <-> Y-row][m=quad*4+r <->
// X-row]: lane owns ONE output row (its Y-row) x 4 consecutive cols per
// n-tile. Both fragments are direct 16B global loads; no LDS anywhere.
// Block = 4 waves = 64 Y-rows x 64 X-rows; wave w owns Y-rows w*16..+15.
// YF32: Y operand is fp32, converted to bf16 in the fragment load.
// mode 0: C fp32 [i][256] + bias[col]                     (final out)
// mode 1: C bf16 q/k layout [b,h,s,e], (acc+bias[col])*scale
// mode 2: C bf16 vT [b][i=d][512 t] + bias[i]             (V^T projection)
// mode 3: C fp32 mid [b][i=s][256 d], no bias             (avg . v)
template <int K, bool YF32>
__global__ __launch_bounds__(256) void gemm_nt(
    const void *__restrict__ Yv, const ushort *__restrict__ X,
    const float *__restrict__ bias, void *__restrict__ Cout, int mode,
    float scale, long yBatch, long xBatch) {
  const int tid = threadIdx.x;
  const int w = tid >> 6, lane = tid & 63;
  const int quad = lane >> 4, l15 = lane & 15;
  const int iLoc = blockIdx.x * 64 + w * 16 + l15;  // this lane's output row
  const int j0 = blockIdx.y * 64;
  const int b = blockIdx.z;

  const ushort *xr[4];
#pragma unroll
  for (int nt = 0; nt < 4; ++nt)
    xr[nt] = X + (long)b * xBatch + (long)(j0 + 16 * nt + l15) * K + quad * 8;
  const float *yf32 = (const float *)Yv + (long)b * yBatch + (long)iLoc * K + quad * 8;
  const ushort *ybf = (const ushort *)Yv + (long)b * yBatch + (long)iLoc * K + quad * 8;

  f32x4 acc[4] = {{0.f, 0.f, 0.f, 0.f},
                  {0.f, 0.f, 0.f, 0.f},
                  {0.f, 0.f, 0.f, 0.f},
                  {0.f, 0.f, 0.f, 0.f}};
#pragma unroll
  for (int ks = 0; ks < K; ks += 32) {
    short8 yfr;
    if (YF32) {
      const float4 a = *(const float4 *)(yf32 + ks);
      const float4 c = *(const float4 *)(yf32 + ks + 4);
      yfr = (short8){(short)f2bf(a.x), (short)f2bf(a.y), (short)f2bf(a.z),
                     (short)f2bf(a.w), (short)f2bf(c.x), (short)f2bf(c.y),
                     (short)f2bf(c.z), (short)f2bf(c.w)};
    } else {
      yfr = *(const short8 *)(ybf + ks);
    }
#pragma unroll
    for (int nt = 0; nt < 4; ++nt) {
      const short8 xfr = *(const short8 *)(xr[nt] + ks);
      acc[nt] = __builtin_amdgcn_mfma_f32_16x16x32_bf16(xfr, yfr, acc[nt], 0, 0, 0);
    }
  }
  // epilogue: lane holds C[iLoc][j0 + 16*nt + 4*quad + r]
#pragma unroll
  for (int nt = 0; nt < 4; ++nt) {
    const int col0 = j0 + 16 * nt + 4 * quad;
    if (mode == 0) {
      const float4 bs = *(const float4 *)(bias + col0);
      float4 st;
      st.x = acc[nt][0] + bs.x; st.y = acc[nt][1] + bs.y;
      st.z = acc[nt][2] + bs.z; st.w = acc[nt][3] + bs.w;
      *(float4 *)((float *)Cout + (long)iLoc * 256 + col0) = st;
    } else if (mode == 1) {
      const float4 bs = *(const float4 *)(bias + col0);
      const int bb = iLoc >> 9, s = iLoc & 511;
      const int h = col0 >> 5, e = col0 & 31;
      ushort4 st;
      st.x = f2bf((acc[nt][0] + bs.x) * scale);
      st.y = f2bf((acc[nt][1] + bs.y) * scale);
      st.z = f2bf((acc[nt][2] + bs.z) * scale);
      st.w = f2bf((acc[nt][3] + bs.w) * scale);
      *(ushort4 *)((ushort *)Cout + (((long)(bb << 3) + h) * 512 + s) * 32 + e) = st;
    } else if (mode == 2) {
      const float bd = bias[iLoc];
      ushort4 st;
      st.x = f2bf(acc[nt][0] + bd); st.y = f2bf(acc[nt][1] + bd);
      st.z = f2bf(acc[nt][2] + bd); st.w = f2bf(acc[nt][3] + bd);
      *(ushort4 *)((ushort *)Cout + ((long)b * 256 + iLoc) * 512 + col0) = st;
    } else {  // mode 3
      float4 st;
      st.x = acc[nt][0]; st.y = acc[nt][1]; st.z = acc[nt][2]; st.w = acc[nt][3];
      *(float4 *)((float *)Cout + ((long)b * 512 + iLoc) * 256 + col0) = st;
    }
  }
}

// Fused scores (MFMA bf16, transposed operands) + diag-mask + sparsemax +
// head-average.  (Unchanged from R7 — verified.)
__global__ __launch_bounds__(256) void attn_sparsemax_mfma(
    const ushort *__restrict__ Q, const ushort *__restrict__ K,
    float *__restrict__ avg) {
  __shared__ f32x4 sc[16 * 128];  // 32 KB score tile, chunk-XOR swizzle
  const int tid = threadIdx.x;
  const int w = tid >> 6, lane = tid & 63;
  const int quad = lane >> 4, l15 = lane & 15;
  const int s0 = blockIdx.x * 16;
  const int b = blockIdx.y;
  const int myrow = 4 * w + quad;
  const int sglob = s0 + myrow;

  float avgacc[8][4] = {};
#pragma unroll 1
  for (int h = 0; h < 8; ++h) {
    const ushort *qh = Q + (((b << 3) + h) * 512 + s0) * 32;
    const ushort *kh = K + ((b << 3) + h) * 512 * 32;
    const short8 bq = *(const short8 *)(qh + l15 * 32 + quad * 8);
    f32x4 acc[8];
#pragma unroll
    for (int jl = 0; jl < 8; ++jl) {
      const short8 ak =
          *(const short8 *)(kh + (w * 128 + jl * 16 + l15) * 32 + quad * 8);
      acc[jl] = __builtin_amdgcn_mfma_f32_16x16x32_bf16(
          ak, bq, (f32x4){0.f, 0.f, 0.f, 0.f}, 0, 0, 0);
    }
    __syncthreads();
#pragma unroll
    for (int jl = 0; jl < 8; ++jl) {
      const int ch = 32 * w + 4 * jl + quad;
      sc[l15 * 128 + (ch ^ (l15 & 7))] = acc[jl];
    }
    __syncthreads();
    f32x4 z[8];
#pragma unroll
    for (int c = 0; c < 8; ++c) {
      const int ch = l15 + 16 * c;
      z[c] = sc[myrow * 128 + (ch ^ (myrow & 7))];
    }
#pragma unroll
    for (int c = 0; c < 8; ++c)
#pragma unroll
      for (int r = 0; r < 4; ++r)
        if (64 * c + 4 * l15 + r == sglob) z[c][r] = -1e30f;
    float M = z[0][0];
#pragma unroll
    for (int c = 0; c < 8; ++c)
#pragma unroll
      for (int r = 0; r < 4; ++r) M = fmaxf(M, z[c][r]);
    M = fmaxf(M, __shfl_xor(M, 1, 64));
    M = fmaxf(M, __shfl_xor(M, 2, 64));
    M = fmaxf(M, __shfl_xor(M, 4, 64));
    M = fmaxf(M, __shfl_xor(M, 8, 64));
    float tau = M - 1.0f;
    int cOld = -1;
#pragma unroll 1
    for (int it = 0; it < 32; ++it) {
      float s = 0.f;
      int c = 0;
#pragma unroll
      for (int cc = 0; cc < 8; ++cc)
#pragma unroll
        for (int r = 0; r < 4; ++r) {
          const bool p = z[cc][r] > tau;
          s += p ? z[cc][r] : 0.f;
          c += p ? 1 : 0;
        }
      s += __shfl_xor(s, 1, 64);
      s += __shfl_xor(s, 2, 64);
      s += __shfl_xor(s, 4, 64);
      s += __shfl_xor(s, 8, 64);
      c += __shfl_xor(c, 1, 64);
      c += __shfl_xor(c, 2, 64);
      c += __shfl_xor(c, 4, 64);
      c += __shfl_xor(c, 8, 64);
      const bool stable = (c == cOld);
      if (__all(stable)) break;
      if (!stable) {
        tau = (s - 1.f) / (float)c;
        cOld = c;
      }
    }
#pragma unroll
    for (int c = 0; c < 8; ++c)
#pragma unroll
      for (int r = 0; r < 4; ++r)
        avgacc[c][r] += fmaxf(z[c][r] - tau, 0.f);
  }
  float *dst = avg + ((b * 512 + sglob) << 9) + 4 * l15;
#pragma unroll
  for (int c = 0; c < 8; ++c) {
    float4 o;
    o.x = avgacc[c][0] * 0.125f;
    o.y = avgacc[c][1] * 0.125f;
    o.z = avgacc[c][2] * 0.125f;
    o.w = avgacc[c][3] * 0.125f;
    *(float4 *)(dst + 64 * c) = o;
  }
}

extern "C" void kernel_launch(void* const* d_in, const int* in_sizes, int n_in,
                              void* d_out, int out_size, void* d_ws, size_t ws_size,
                              hipStream_t stream) {
  const float *x  = (const float *)d_in[0];
  const float *Wq = (const float *)d_in[1];
  const float *bq = (const float *)d_in[2];
  const float *Wk = (const float *)d_in[3];
  const float *bk = (const float *)d_in[4];
  const float *Wv = (const float *)d_in[5];
  const float *bv = (const float *)d_in[6];
  const float *Wo = (const float *)d_in[7];
  const float *bo = (const float *)d_in[8];

  float *out = (float *)d_out;                 // [B,S,D]
  float *avg = out + 32 * 512 * 256;           // [B,S,S] fp32

  // ws (ushort units): xbf | qbf | kbf | vT | wbf  = 34.1 MB peak.
  // mid (fp32, 16.78 MB) overlays xbf+qbf after both are dead.
  ushort *ws16 = (ushort *)d_ws;
  ushort *xbf = ws16;                          // [16384][256] bf16
  ushort *qbf = ws16 + 4194304;                // [B,H,S,32] bf16 (pre-scaled)
  ushort *kbf = ws16 + 8388608;                // [B,H,S,32] bf16
  ushort *vT  = ws16 + 12582912;               // [B][256 d][512 t] bf16
  ushort *wbf = ws16 + 16777216;               // Wq|Wk|Wv|Wo bf16, 65536 each
  float  *mid = (float *)d_ws;                 // [B][512][256] fp32 (overlay)

  cvt_bf16<<<dim3(4352), dim3(256), 0, stream>>>(x, Wq, Wk, Wv, Wo, xbf, wbf);
  // Q/K projections: i = global token row, j = dout; X = weight rows.
  gemm_nt<256, false><<<dim3(256, 4, 1), dim3(256), 0, stream>>>(
      xbf, wbf, bq, qbf, 1, SCALE_QK, 0, 0);
  gemm_nt<256, false><<<dim3(256, 4, 1), dim3(256), 0, stream>>>(
      xbf, wbf + 65536, bk, kbf, 1, 1.0f, 0, 0);
  // V^T projection: i = d (Y = Wv rows), j = t (X = xbf rows of batch b).
  gemm_nt<256, false><<<dim3(4, 8, 32), dim3(256), 0, stream>>>(
      wbf + 131072, xbf, bv, vT, 2, 1.0f, 0, 131072);
  attn_sparsemax_mfma<<<dim3(32, 32), dim3(256), 0, stream>>>(qbf, kbf, avg);
  // mid = avg . v : i = s (Y = avg rows, fp32 cvt), j = d (X = vT rows).
  gemm_nt<512, true><<<dim3(8, 4, 32), dim3(256), 0, stream>>>(
      avg, vT, nullptr, mid, 3, 1.0f, 262144, 131072);
  // final projection: i = global token row (Y = mid fp32), j = e (X = Wo).
  gemm_nt<256, true><<<dim3(256, 4, 1), dim3(256), 0, stream>>>(
      mid, wbf + 196608, bo, out, 0, 1.0f, 0, 0);
}

// Round 9
// 288.569 us; speedup vs baseline: 1.7910x; 1.0698x over previous
//
#include <hip/hip_runtime.h>
#include <hip/hip_bf16.h>

// Problem constants: B=32, S=512, D=256, H=8, DH=32
#define SCALE_QK 0.17677669529663687f  // 1/sqrt(32)

typedef __attribute__((ext_vector_type(8))) short short8;  // 8 bf16 (4 VGPRs)
typedef __attribute__((ext_vector_type(4))) float f32x4;

__device__ __forceinline__ ushort f2bf(float f) {  // fp32 -> bf16 RNE
  unsigned u = __float_as_uint(f);
  return (ushort)((u + 0x7FFF + ((u >> 16) & 1)) >> 16);
}

// DPP lane-move within rows of 16 (our reduction groups are exactly DPP rows).
template <int CTRL>
__device__ __forceinline__ float dpp_movf(float x) {
  return __int_as_float(
      __builtin_amdgcn_update_dpp(0, __float_as_int(x), CTRL, 0xF, 0xF, true));
}
// 16-lane sum/max via quad_perm xor1 (0xB1), xor2 (0x4E), row_half_mirror
// (0x141), row_mirror (0x140) — all lanes end with the full reduction.
__device__ __forceinline__ float dpp_sum16(float x) {
  x += dpp_movf<0xB1>(x);
  x += dpp_movf<0x4E>(x);
  x += dpp_movf<0x141>(x);
  x += dpp_movf<0x140>(x);
  return x;
}
__device__ __forceinline__ float dpp_max16(float x) {
  x = fmaxf(x, dpp_movf<0xB1>(x));
  x = fmaxf(x, dpp_movf<0x4E>(x));
  x = fmaxf(x, dpp_movf<0x141>(x));
  x = fmaxf(x, dpp_movf<0x140>(x));
  return x;
}

// Convert x (16384x256 fp32) and Wq, Wk (256x256) to bf16.
__global__ __launch_bounds__(256) void cvt_bf16(
    const float *__restrict__ x, const float *__restrict__ w0,
    const float *__restrict__ w1, ushort *__restrict__ xbf,
    ushort *__restrict__ wbf) {
  const long i = (long)blockIdx.x * 256 + threadIdx.x;  // one float4 each
  const long NX4 = 16384L * 256 / 4;                    // 1048576
  const float *src;
  ushort4 *dst;
  long k;
  if (i < NX4) {
    src = x; k = i; dst = (ushort4 *)xbf;
  } else {
    const long j = i - NX4;  // [0, 32768)
    const int which = (int)(j >> 14);
    k = j & 16383;
    src = which == 0 ? w0 : w1;
    dst = (ushort4 *)(wbf + which * 65536L);
  }
  const float4 v = ((const float4 *)src)[k];
  ushort4 o;
  o.x = f2bf(v.x); o.y = f2bf(v.y); o.z = f2bf(v.z); o.w = f2bf(v.w);
  dst[k] = o;
}

// Wvo[e][m] = sum_d Wo[e][d] * Wv[d][m]  (bf16 out);  bvo = Wo.bv + bo (fp32).
// out = avg.(v.Wo^T + bo) is exact because sparsemax rows sum to 1.
__global__ __launch_bounds__(256) void make_wvo(
    const float *__restrict__ Wo, const float *__restrict__ Wv,
    const float *__restrict__ bv, const float *__restrict__ bo,
    ushort *__restrict__ wvo, float *__restrict__ bvo) {
  const int e = blockIdx.x, m = threadIdx.x;
  float acc = 0.f;
  for (int d = 0; d < 256; ++d) acc += Wo[e * 256 + d] * Wv[d * 256 + m];
  wvo[e * 256 + m] = f2bf(acc);
  if (m == 0) {
    float s = 0.f;
    for (int d = 0; d < 256; ++d) s += Wo[e * 256 + d] * bv[d];
    bvo[e] = s + bo[e];
  }
}

// Unified NT bf16 MFMA GEMM: C[i][j] = dot(Y-row i, X-row j) (+bias).
// mfma(A=X-tile rows, B=Y-tile rows) -> lane owns ONE output row (its Y-row)
// x 4 consecutive cols per n-tile. Both fragments direct 16B loads; no LDS.
// YF32: Y operand is fp32, converted to bf16 in the fragment load.
// mode 1: C bf16 q/k layout [b,h,s,e], (acc+bias[col])*scale
// mode 2: C bf16 T-layout [b][i][512 t] + bias[i]         (u^T projection)
// mode 3: C fp32 [b][i][256 j], no bias                   (final out)
template <int K, bool YF32>
__global__ __launch_bounds__(256) void gemm_nt(
    const void *__restrict__ Yv, const ushort *__restrict__ X,
    const float *__restrict__ bias, void *__restrict__ Cout, int mode,
    float scale, long yBatch, long xBatch) {
  const int tid = threadIdx.x;
  const int w = tid >> 6, lane = tid & 63;
  const int quad = lane >> 4, l15 = lane & 15;
  const int iLoc = blockIdx.x * 64 + w * 16 + l15;  // this lane's output row
  const int j0 = blockIdx.y * 64;
  const int b = blockIdx.z;

  const ushort *xr[4];
#pragma unroll
  for (int nt = 0; nt < 4; ++nt)
    xr[nt] = X + (long)b * xBatch + (long)(j0 + 16 * nt + l15) * K + quad * 8;
  const float *yf32 = (const float *)Yv + (long)b * yBatch + (long)iLoc * K + quad * 8;
  const ushort *ybf = (const ushort *)Yv + (long)b * yBatch + (long)iLoc * K + quad * 8;

  f32x4 acc[4] = {{0.f, 0.f, 0.f, 0.f},
                  {0.f, 0.f, 0.f, 0.f},
                  {0.f, 0.f, 0.f, 0.f},
                  {0.f, 0.f, 0.f, 0.f}};
#pragma unroll
  for (int ks = 0; ks < K; ks += 32) {
    short8 yfr;
    if (YF32) {
      const float4 a = *(const float4 *)(yf32 + ks);
      const float4 c = *(const float4 *)(yf32 + ks + 4);
      yfr = (short8){(short)f2bf(a.x), (short)f2bf(a.y), (short)f2bf(a.z),
                     (short)f2bf(a.w), (short)f2bf(c.x), (short)f2bf(c.y),
                     (short)f2bf(c.z), (short)f2bf(c.w)};
    } else {
      yfr = *(const short8 *)(ybf + ks);
    }
#pragma unroll
    for (int nt = 0; nt < 4; ++nt) {
      const short8 xfr = *(const short8 *)(xr[nt] + ks);
      acc[nt] = __builtin_amdgcn_mfma_f32_16x16x32_bf16(xfr, yfr, acc[nt], 0, 0, 0);
    }
  }
  // epilogue: lane holds C[iLoc][j0 + 16*nt + 4*quad + r]
#pragma unroll
  for (int nt = 0; nt < 4; ++nt) {
    const int col0 = j0 + 16 * nt + 4 * quad;
    if (mode == 1) {
      const float4 bs = *(const float4 *)(bias + col0);
      const int bb = iLoc >> 9, s = iLoc & 511;
      const int h = col0 >> 5, e = col0 & 31;
      ushort4 st;
      st.x = f2bf((acc[nt][0] + bs.x) * scale);
      st.y = f2bf((acc[nt][1] + bs.y) * scale);
      st.z = f2bf((acc[nt][2] + bs.z) * scale);
      st.w = f2bf((acc[nt][3] + bs.w) * scale);
      *(ushort4 *)((ushort *)Cout + (((long)(bb << 3) + h) * 512 + s) * 32 + e) = st;
    } else if (mode == 2) {
      const float bd = bias[iLoc];
      ushort4 st;
      st.x = f2bf(acc[nt][0] + bd); st.y = f2bf(acc[nt][1] + bd);
      st.z = f2bf(acc[nt][2] + bd); st.w = f2bf(acc[nt][3] + bd);
      *(ushort4 *)((ushort *)Cout + ((long)b * 256 + iLoc) * 512 + col0) = st;
    } else {  // mode 3
      float4 st;
      st.x = acc[nt][0]; st.y = acc[nt][1]; st.z = acc[nt][2]; st.w = acc[nt][3];
      *(float4 *)((float *)Cout + ((long)b * 512 + iLoc) * 256 + col0) = st;
    }
  }
}

// Fused scores (MFMA bf16, transposed operands) + diag-mask + sparsemax +
// head-average.  R7 structure; all 16-lane reductions now DPP (VALU) instead
// of shfl_xor (DS) — the solve layout's row groups are exactly DPP rows.
__global__ __launch_bounds__(256) void attn_sparsemax_mfma(
    const ushort *__restrict__ Q, const ushort *__restrict__ K,
    float *__restrict__ avg) {
  __shared__ f32x4 sc[16 * 128];  // 32 KB score tile, chunk-XOR swizzle
  const int tid = threadIdx.x;
  const int w = tid >> 6, lane = tid & 63;
  const int quad = lane >> 4, l15 = lane & 15;
  const int s0 = blockIdx.x * 16;
  const int b = blockIdx.y;
  const int myrow = 4 * w + quad;
  const int sglob = s0 + myrow;

  float avgacc[8][4] = {};
#pragma unroll 1
  for (int h = 0; h < 8; ++h) {
    const ushort *qh = Q + (((b << 3) + h) * 512 + s0) * 32;
    const ushort *kh = K + ((b << 3) + h) * 512 * 32;
    const short8 bq = *(const short8 *)(qh + l15 * 32 + quad * 8);
    f32x4 acc[8];
#pragma unroll
    for (int jl = 0; jl < 8; ++jl) {
      const short8 ak =
          *(const short8 *)(kh + (w * 128 + jl * 16 + l15) * 32 + quad * 8);
      acc[jl] = __builtin_amdgcn_mfma_f32_16x16x32_bf16(
          ak, bq, (f32x4){0.f, 0.f, 0.f, 0.f}, 0, 0, 0);
    }
    __syncthreads();
#pragma unroll
    for (int jl = 0; jl < 8; ++jl) {
      const int ch = 32 * w + 4 * jl + quad;
      sc[l15 * 128 + (ch ^ (l15 & 7))] = acc[jl];
    }
    __syncthreads();
    f32x4 z[8];
#pragma unroll
    for (int c = 0; c < 8; ++c) {
      const int ch = l15 + 16 * c;
      z[c] = sc[myrow * 128 + (ch ^ (myrow & 7))];
    }
#pragma unroll
    for (int c = 0; c < 8; ++c)
#pragma unroll
      for (int r = 0; r < 4; ++r)
        if (64 * c + 4 * l15 + r == sglob) z[c][r] = -1e30f;
    float M = z[0][0];
#pragma unroll
    for (int c = 0; c < 8; ++c)
#pragma unroll
      for (int r = 0; r < 4; ++r) M = fmaxf(M, z[c][r]);
    M = dpp_max16(M);
    float tau = M - 1.0f;
    float cOld = -1.f;
#pragma unroll 1
    for (int it = 0; it < 32; ++it) {
      float s = 0.f, c = 0.f;
#pragma unroll
      for (int cc = 0; cc < 8; ++cc)
#pragma unroll
        for (int r = 0; r < 4; ++r) {
          const bool p = z[cc][r] > tau;
          s += p ? z[cc][r] : 0.f;
          c += p ? 1.f : 0.f;
        }
      s = dpp_sum16(s);
      c = dpp_sum16(c);
      const bool stable = (c == cOld);
      if (__all(stable)) break;  // all supports fixed -> taus exact
      if (!stable) {
        tau = (s - 1.f) / c;
        cOld = c;
      }
    }
#pragma unroll
    for (int c = 0; c < 8; ++c)
#pragma unroll
      for (int r = 0; r < 4; ++r)
        avgacc[c][r] += fmaxf(z[c][r] - tau, 0.f);
  }
  float *dst = avg + ((b * 512 + sglob) << 9) + 4 * l15;
#pragma unroll
  for (int c = 0; c < 8; ++c) {
    float4 o;
    o.x = avgacc[c][0] * 0.125f;
    o.y = avgacc[c][1] * 0.125f;
    o.z = avgacc[c][2] * 0.125f;
    o.w = avgacc[c][3] * 0.125f;
    *(float4 *)(dst + 64 * c) = o;
  }
}

extern "C" void kernel_launch(void* const* d_in, const int* in_sizes, int n_in,
                              void* d_out, int out_size, void* d_ws, size_t ws_size,
                              hipStream_t stream) {
  const float *x  = (const float *)d_in[0];
  const float *Wq = (const float *)d_in[1];
  const float *bq = (const float *)d_in[2];
  const float *Wk = (const float *)d_in[3];
  const float *bk = (const float *)d_in[4];
  const float *Wv = (const float *)d_in[5];
  const float *bv = (const float *)d_in[6];
  const float *Wo = (const float *)d_in[7];
  const float *bo = (const float *)d_in[8];

  float *out = (float *)d_out;                 // [B,S,D]
  float *avg = out + 32 * 512 * 256;           // [B,S,S] fp32

  // ws (ushort units): xbf | qbf | kbf | uT | wq,wk,wvo | bvo  ~= 33.9 MB
  ushort *ws16 = (ushort *)d_ws;
  ushort *xbf = ws16;                          // [16384][256] bf16
  ushort *qbf = ws16 + 4194304;                // [B,H,S,32] bf16 (pre-scaled)
  ushort *kbf = ws16 + 8388608;                // [B,H,S,32] bf16
  ushort *uT  = ws16 + 12582912;               // [B][256 e][512 t] bf16
  ushort *wbf = ws16 + 16777216;               // Wq|Wk|Wvo bf16, 65536 each
  float  *bvo = (float *)(ws16 + 16973824);    // [256] fp32

  cvt_bf16<<<dim3(4224), dim3(256), 0, stream>>>(x, Wq, Wk, xbf, wbf);
  make_wvo<<<dim3(256), dim3(256), 0, stream>>>(Wo, Wv, bv, bo,
                                                wbf + 131072, bvo);
  // Q/K projections: i = global token row, j = dout; X = weight rows.
  gemm_nt<256, false><<<dim3(256, 4, 1), dim3(256), 0, stream>>>(
      xbf, wbf, bq, qbf, 1, SCALE_QK, 0, 0);
  gemm_nt<256, false><<<dim3(256, 4, 1), dim3(256), 0, stream>>>(
      xbf, wbf + 65536, bk, kbf, 1, 1.0f, 0, 0);
  // u^T projection: i = e (Y = Wvo rows), j = t (X = xbf rows of batch b).
  gemm_nt<256, false><<<dim3(4, 8, 32), dim3(256), 0, stream>>>(
      wbf + 131072, xbf, bvo, uT, 2, 1.0f, 0, 131072);
  attn_sparsemax_mfma<<<dim3(32, 32), dim3(256), 0, stream>>>(qbf, kbf, avg);
  // out = avg . u : i = s (Y = avg rows, fp32 cvt), j = e (X = uT rows).
  gemm_nt<512, true><<<dim3(8, 4, 32), dim3(256), 0, stream>>>(
      avg, uT, nullptr, out, 3, 1.0f, 262144, 131072);
}